// Round 4
// baseline (214.114 us; speedup 1.0000x reference)
//
#include <hip/hip_runtime.h>
#include <hip/hip_fp16.h>

#define LOG2E 1.44269504088896340736f
#define DM 1536
#define LL  2048
#define NN  16
#define NCH 256    // chunks per row (4 waves x 64 lanes)
#define CL  8      // steps per chunk = LL / NCH

__device__ __forceinline__ float fexp2(float v){ return __builtin_amdgcn_exp2f(v); }
__device__ __forceinline__ float frcp(float v){ return __builtin_amdgcn_rcpf(v); }

// pack {d*LOG2E, d*x} as half2 in a float: exp2 inputs use dl*A_raw (A stays
// in SGPRs), h-update uses dx directly as an f16 fma_mix operand.
__device__ __forceinline__ float packdx(float d, float x){
    return __builtin_bit_cast(float, __floats2half2_rn(d*LOG2E, d*x));
}
// force a block-uniform float into an SGPR
__device__ __forceinline__ float to_sgpr(float v){
    return __builtin_bit_cast(float, __builtin_amdgcn_readfirstlane(__builtin_bit_cast(int, v)));
}

// B,C fp32 [b][n][t] -> fp16 records: BC[((b*8 + (t&7))*256 + (t>>3))*32 + n]
// (B at +n, C at +16+n). Per (step r, chunk c) one contiguous 64 B record;
// per r the 256 chunks form one 16 KB slab read coalesced by 4 waves.
__global__ __launch_bounds__(256) void transpose_bc(
        const float* __restrict__ Bm, const float* __restrict__ Cm,
        __half* __restrict__ BC){
    const int q  = blockIdx.x*256 + threadIdx.x;   // 16384 float4 quads
    const int t0 = (q & 511) << 2;
    const int n  = (q >> 9) & 15;
    const int b  = q >> 13;
    const long i = (long)(b*NN + n)*LL + t0;
    const float4 bv = *(const float4*)(Bm + i);
    const float4 cv = *(const float4*)(Cm + i);
    const float bb[4]={bv.x,bv.y,bv.z,bv.w}, cc[4]={cv.x,cv.y,cv.z,cv.w};
#pragma unroll
    for (int j=0;j<4;++j){
        const int t = t0 + j;
        const long o = ((long)((b*CL + (t&7))*NCH + (t>>3)))*32 + n;
        BC[o]      = __float2half_rn(bb[j]);
        BC[o + 16] = __float2half_rn(cc[j]);
    }
}

// Block = 4 waves = ONE row-pair (2 consecutive d, same b): keeps the 2-rows-
// per-record unpack amortization (round 3 showed dropping it costs +50% VALU).
// Register diet vs round 2 (which spilled at the same shape):
//  - A rows pinned to SGPRs via readfirstlane; LOG2E folded into packed d.
//  - B/C stay packed fp16 in registers; consumed via v_fma_mix (fpext folded
//    into the FMA by the compiler) -> no fp32 bb[16]/cc[16] arrays.
//  - #pragma unroll 1 + explicit 1-step prefetch (record + wd) instead of
//    unroll 2 -> one packed set in flight, not two unpacked ones.
// Live ~85 VGPR -> __launch_bounds__(256,5) (budget 102) = 5 waves/SIMD,
// 20 waves/CU, no spill. Grid 1536 = 6 blocks/CU even. LDS 17.4 KB.
// x*D moved to the epilogue (x re-read there; L3-resident).
__global__ __launch_bounds__(256, 5) void ssm_scan(
    const float* __restrict__ x, const float* __restrict__ delta,
    const float* __restrict__ A, const float* __restrict__ Dv,
    const float* __restrict__ z, const __half* __restrict__ BC,
    float* __restrict__ out)
{
    __shared__ float2 sdx[CL*NCH];     // 16 KB
    __shared__ float  wtP[4][2][NN];   // per-wave inclusive totals
    __shared__ float  wtG[4][2][NN];

    const int lane = threadIdx.x & 63;
    const int w    = threadIdx.x >> 6;
    const int cmy  = threadIdx.x;            // my chunk (0..255)
    const int row0 = blockIdx.x*2;           // b*DM + d ; row1 = row0+1
    const int b    = (row0 >= DM) ? 1 : 0;
    const int d0   = row0 - b*DM;

    const long base0 = (long)row0*LL;
    const long base1 = base0 + LL;
    const float* gd0 = delta + base0; const float* gx0 = x + base0;
    const float* gd1 = delta + base1; const float* gx1 = x + base1;

    // ---- stage packed (dl,dx) for both rows; wave w covers t in [w*512,+512)
    for (int k=0;k<512;k+=256){
        const int t0 = w*512 + k + lane*4;
        const float4 dv0 = *(const float4*)(gd0 + t0);
        const float4 xv0 = *(const float4*)(gx0 + t0);
        const float4 dv1 = *(const float4*)(gd1 + t0);
        const float4 xv1 = *(const float4*)(gx1 + t0);
        const float dd0[4]={dv0.x,dv0.y,dv0.z,dv0.w}, xx0[4]={xv0.x,xv0.y,xv0.z,xv0.w};
        const float dd1[4]={dv1.x,dv1.y,dv1.z,dv1.w}, xx1[4]={xv1.x,xv1.y,xv1.z,xv1.w};
#pragma unroll
        for (int j=0;j<4;++j){
            const int t = t0 + j, r = t & 7, c = t >> 3;
            float2 wd; wd.x = packdx(dd0[j], xx0[j]); wd.y = packdx(dd1[j], xx1[j]);
            sdx[r*NCH + c] = wd;
        }
    }

    // A rows -> SGPRs (block-uniform). Raw A; LOG2E already folded into dl.
    float Ar0[NN], Ar1[NN];
#pragma unroll
    for (int n=0;n<NN;++n){
        Ar0[n] = to_sgpr(A[d0*NN + n]);
        Ar1[n] = to_sgpr(A[(d0+1)*NN + n]);
    }

    // record for (b, r, chunk cmy): BC + b*65536 + r*8192 + cmy*32 (halfs)
    const __half* bc = BC + (long)b*65536 + cmy*32;

    // ---- phase 1: local chunk scan h0=0 -> G (both rows); sum(dl) -> P
    float G0[NN], G1[NN];
#pragma unroll
    for (int n=0;n<NN;++n){ G0[n]=0.f; G1[n]=0.f; }
    float dsl0=0.f, dsl1=0.f;
    {
        float4 rb0 = ((const float4*)bc)[0];
        float4 rb1 = ((const float4*)bc)[1];
        float2 wdc = sdx[cmy];
#pragma unroll 1
        for (int r=0;r<CL;++r){
            const int rn = (r<CL-1) ? r+1 : r;
            const float4* nrec = (const float4*)(bc + (long)rn*8192);
            const float4 nb0 = nrec[0], nb1 = nrec[1];
            const float2 nwd = sdx[rn*NCH + cmy];

            const __half2 q0 = __builtin_bit_cast(__half2, wdc.x);
            const __half2 q1 = __builtin_bit_cast(__half2, wdc.y);
            const float dl0 = __half2float(q0.x);
            const float dl1 = __half2float(q1.x);
            dsl0 += dl0; dsl1 += dl1;
            const float pb[8] = {rb0.x,rb0.y,rb0.z,rb0.w, rb1.x,rb1.y,rb1.z,rb1.w};
#pragma unroll
            for (int n=0;n<NN;++n){
                const __half2 b2 = __builtin_bit_cast(__half2, pb[n>>1]);
                const __half  bh = (n&1) ? b2.y : b2.x;
                const float e0 = fexp2(dl0*Ar0[n]);
                G0[n] = __builtin_fmaf(__half2float(bh), __half2float(q0.y), e0*G0[n]);
                const float e1 = fexp2(dl1*Ar1[n]);
                G1[n] = __builtin_fmaf(__half2float(bh), __half2float(q1.y), e1*G1[n]);
            }
            rb0 = nb0; rb1 = nb1; wdc = nwd;
        }
    }

    // ---- phase 2: two-level scan (KS within wave, serial compose across 4 waves)
    float h0[NN], h1[NN];
    {
        float P0[NN], P1[NN];
#pragma unroll
        for (int n=0;n<NN;++n){ P0[n]=fexp2(dsl0*Ar0[n]); P1[n]=fexp2(dsl1*Ar1[n]); }
        // inclusive Kogge-Stone within wave
#pragma unroll
        for (int s=1;s<64;s<<=1){
#pragma unroll
            for (int n=0;n<NN;++n){
                const float pl0=__shfl_up(P0[n],s), gl0=__shfl_up(G0[n],s);
                const float pl1=__shfl_up(P1[n],s), gl1=__shfl_up(G1[n],s);
                if (lane >= s){
                    G0[n]=__builtin_fmaf(P0[n],gl0,G0[n]); P0[n]*=pl0;
                    G1[n]=__builtin_fmaf(P1[n],gl1,G1[n]); P1[n]*=pl1;
                }
            }
        }
        // every wave publishes its inclusive total
        if (lane==63){
#pragma unroll
            for (int n=0;n<NN;++n){
                wtP[w][0][n]=P0[n]; wtG[w][0][n]=G0[n];
                wtP[w][1][n]=P1[n]; wtG[w][1][n]=G1[n];
            }
        }
        __syncthreads();
        // exclusive within wave, then compose with prefix of preceding waves
#pragma unroll
        for (int n=0;n<NN;++n){
            const float pe0=__shfl_up(P0[n],1), ge0=__shfl_up(G0[n],1);
            const float pe1=__shfl_up(P1[n],1), ge1=__shfl_up(G1[n],1);
            const float Px0 = (lane==0)?1.f:pe0, Gx0 = (lane==0)?0.f:ge0;
            const float Px1 = (lane==0)?1.f:pe1, Gx1 = (lane==0)?0.f:ge1;
            float gp0 = 0.f, gp1 = 0.f;
            for (int wv=0; wv<w; ++wv){          // wave-uniform trip count
                gp0 = __builtin_fmaf(wtP[wv][0][n], gp0, wtG[wv][0][n]);
                gp1 = __builtin_fmaf(wtP[wv][1][n], gp1, wtG[wv][1][n]);
            }
            h0[n] = __builtin_fmaf(Px0, gp0, Gx0);
            h1[n] = __builtin_fmaf(Px1, gp1, Gx1);
        }
    }

    // ---- phase 3: re-scan with true h_start; stash fp32 {y0,y1} in the slot
    {
        float4 rb0 = ((const float4*)bc)[0];
        float4 rb1 = ((const float4*)bc)[1];
        float4 rc0 = ((const float4*)bc)[2];
        float4 rc1 = ((const float4*)bc)[3];
        float2 wdc = sdx[cmy];
#pragma unroll 1
        for (int r=0;r<CL;++r){
            const int rn = (r<CL-1) ? r+1 : r;
            const float4* nrec = (const float4*)(bc + (long)rn*8192);
            const float4 nb0 = nrec[0], nb1 = nrec[1];
            const float4 nc0 = nrec[2], nc1 = nrec[3];
            const float2 nwd = sdx[rn*NCH + cmy];   // read-before-write ok at r=7

            const __half2 q0 = __builtin_bit_cast(__half2, wdc.x);
            const __half2 q1 = __builtin_bit_cast(__half2, wdc.y);
            const float dl0 = __half2float(q0.x);
            const float dl1 = __half2float(q1.x);
            const float pb[8] = {rb0.x,rb0.y,rb0.z,rb0.w, rb1.x,rb1.y,rb1.z,rb1.w};
            const float pc[8] = {rc0.x,rc0.y,rc0.z,rc0.w, rc1.x,rc1.y,rc1.z,rc1.w};
            float ya0=0.f, yb0=0.f, ya1=0.f, yb1=0.f;
#pragma unroll
            for (int n=0;n<NN;++n){
                const __half2 b2 = __builtin_bit_cast(__half2, pb[n>>1]);
                const __half2 c2 = __builtin_bit_cast(__half2, pc[n>>1]);
                const __half  bh = (n&1) ? b2.y : b2.x;
                const __half  ch = (n&1) ? c2.y : c2.x;
                const float e0 = fexp2(dl0*Ar0[n]);
                h0[n] = __builtin_fmaf(__half2float(bh), __half2float(q0.y), e0*h0[n]);
                const float e1 = fexp2(dl1*Ar1[n]);
                h1[n] = __builtin_fmaf(__half2float(bh), __half2float(q1.y), e1*h1[n]);
                if (n&1){ yb0 = __builtin_fmaf(__half2float(ch), h0[n], yb0);
                          yb1 = __builtin_fmaf(__half2float(ch), h1[n], yb1); }
                else    { ya0 = __builtin_fmaf(__half2float(ch), h0[n], ya0);
                          ya1 = __builtin_fmaf(__half2float(ch), h1[n], ya1); }
            }
            float2 yo; yo.x = ya0+yb0; yo.y = ya1+yb1;
            sdx[r*NCH + cmy] = yo;              // same-wave slot, no barrier
            rb0=nb0; rb1=nb1; rc0=nc0; rc1=nc1; wdc=nwd;
        }
    }

    // ---- epilogue: stream z and x once, coalesced float4 in/out
    // wave w reads t in [w*512,+512) -> chunks [w*64,+64): same-wave slots only
    const float Dd0 = to_sgpr(Dv[d0]), Dd1 = to_sgpr(Dv[d0+1]);
    const float* gz0 = z + base0; const float* gz1 = z + base1;
    float* go0 = out + base0;     float* go1 = out + base1;
    for (int k=0;k<512;k+=256){
        const int t0 = w*512 + k + lane*4;
        const float4 zv0 = *(const float4*)(gz0 + t0);
        const float4 zv1 = *(const float4*)(gz1 + t0);
        const float4 xv0 = *(const float4*)(gx0 + t0);
        const float4 xv1 = *(const float4*)(gx1 + t0);
        const float zz0[4]={zv0.x,zv0.y,zv0.z,zv0.w}, zz1[4]={zv1.x,zv1.y,zv1.z,zv1.w};
        const float xx0[4]={xv0.x,xv0.y,xv0.z,xv0.w}, xx1[4]={xv1.x,xv1.y,xv1.z,xv1.w};
        float o0[4], o1[4];
#pragma unroll
        for (int j=0;j<4;++j){
            const int t = t0 + j, r = t & 7, c = t >> 3;
            const float2 wd = sdx[r*NCH + c];
            const float s0 = frcp(1.f + fexp2(-zz0[j]*LOG2E));
            const float s1 = frcp(1.f + fexp2(-zz1[j]*LOG2E));
            o0[j] = __builtin_fmaf(xx0[j], Dd0, wd.x) * (zz0[j]*s0);
            o1[j] = __builtin_fmaf(xx1[j], Dd1, wd.y) * (zz1[j]*s1);
        }
        float4 a  = {o0[0],o0[1],o0[2],o0[3]};
        float4 bq = {o1[0],o1[1],o1[2],o1[3]};
        *(float4*)(go0 + t0) = a;
        *(float4*)(go1 + t0) = bq;
    }
}

extern "C" void kernel_launch(void* const* d_in, const int* in_sizes, int n_in,
                              void* d_out, int out_size, void* d_ws, size_t ws_size,
                              hipStream_t stream) {
    const float* x     = (const float*)d_in[0];
    const float* delta = (const float*)d_in[1];
    const float* A     = (const float*)d_in[2];
    const float* B     = (const float*)d_in[3];
    const float* C     = (const float*)d_in[4];
    const float* Dv    = (const float*)d_in[5];
    const float* z     = (const float*)d_in[6];
    float* out = (float*)d_out;

    __half* BC = (__half*)d_ws;               // 131072 halfs = 256 KB

    transpose_bc<<<dim3(64), dim3(256), 0, stream>>>(B, C, BC);
    ssm_scan<<<dim3(DM), dim3(256), 0, stream>>>(x, delta, A, Dv, z, BC, out);
}

// Round 5
// 162.567 us; speedup vs baseline: 1.3171x; 1.3171x over previous
//
#include <hip/hip_runtime.h>
#include <hip/hip_fp16.h>

#define LOG2E 1.44269504088896340736f
#define LN2   0.69314718055994530942f
#define DM 1536
#define LL  2048
#define NN  16
#define NCH 256    // chunks per row (4 waves x 64 lanes)
#define CL  8      // steps per chunk = LL / NCH

__device__ __forceinline__ float fexp2(float v){ return __builtin_amdgcn_exp2f(v); }
__device__ __forceinline__ float frcp(float v){ return __builtin_amdgcn_rcpf(v); }

// pack {d*LOG2E, x} as half2 in a float. exp2 args use dl*A_raw (A in SGPRs);
// dx is recovered as (dl*LN2)*x (2 muls) so x stays available for the x*D term.
__device__ __forceinline__ float packdx(float d, float x){
    return __builtin_bit_cast(float, __floats2half2_rn(d*LOG2E, x));
}
__device__ __forceinline__ void unpackdx(float f, float& dl, float& x){
    const float2 p = __half22float2(__builtin_bit_cast(__half2, f));
    dl = p.x; x = p.y;
}
// float4 = 8 packed halfs -> 8 floats
__device__ __forceinline__ void unpack8(const float4 f, float* o){
    float2 p;
    p = __half22float2(__builtin_bit_cast(__half2, f.x)); o[0]=p.x; o[1]=p.y;
    p = __half22float2(__builtin_bit_cast(__half2, f.y)); o[2]=p.x; o[3]=p.y;
    p = __half22float2(__builtin_bit_cast(__half2, f.z)); o[4]=p.x; o[5]=p.y;
    p = __half22float2(__builtin_bit_cast(__half2, f.w)); o[6]=p.x; o[7]=p.y;
}
// force a block-uniform float into an SGPR
__device__ __forceinline__ float to_sgpr(float v){
    return __builtin_bit_cast(float, __builtin_amdgcn_readfirstlane(__builtin_bit_cast(int, v)));
}

// B,C fp32 [b][n][t] -> fp16 records: BC[((b*8 + (t&7))*256 + (t>>3))*32 + n]
// (B at +n, C at +16+n). Per (step r, chunk c) one contiguous 64 B record;
// per r the 256 chunks form one 16 KB slab read coalesced by 4 waves.
__global__ __launch_bounds__(256) void transpose_bc(
        const float* __restrict__ Bm, const float* __restrict__ Cm,
        __half* __restrict__ BC){
    const int q  = blockIdx.x*256 + threadIdx.x;   // 16384 float4 quads
    const int t0 = (q & 511) << 2;
    const int n  = (q >> 9) & 15;
    const int b  = q >> 13;
    const long i = (long)(b*NN + n)*LL + t0;
    const float4 bv = *(const float4*)(Bm + i);
    const float4 cv = *(const float4*)(Cm + i);
    const float bb[4]={bv.x,bv.y,bv.z,bv.w}, cc[4]={cv.x,cv.y,cv.z,cv.w};
#pragma unroll
    for (int j=0;j<4;++j){
        const int t = t0 + j;
        const long o = ((long)((b*CL + (t&7))*NCH + (t>>3)))*32 + n;
        BC[o]      = __float2half_rn(bb[j]);
        BC[o + 16] = __float2half_rn(cc[j]);
    }
}

// Block = 4 waves = ONE row-pair (2 consecutive d, same b). Keeps round-0's
// proven fp32-array inner loops (fp16 consumed only via unpack8, once per
// record) and round-0's pair-row amortization (R3 showed single-row = +50%
// issue work). Register budget: __launch_bounds__(256,4) = 128 VGPR, the
// first budget >= the scheme's ~110-125 live set (85/102 both spilled:
// R2 275 MB, R4 54 MB of scratch; R0 fit at 170 with 9 MB).
//  - A rows in SGPRs via readfirstlane (-32 VGPR vs R0).
//  - phase 3 unroll 1 + explicit prefetch of the RAW packed next record
//    (16 regs) instead of R0's unroll 2 (two unpacked fp32 sets = +32).
//  - {d*LOG2E, x} packed half2; dx = (dl*LN2)*x recovered in-loop.
// Occupancy: grid 1536 x 4 waves = 24 waves/CU supply, VGPR-limited to
// 4/SIMD = 16 waves/CU (R0: 12). LDS 17.4 KB.
__global__ __launch_bounds__(256, 4) void ssm_scan(
    const float* __restrict__ x, const float* __restrict__ delta,
    const float* __restrict__ A, const float* __restrict__ Dv,
    const float* __restrict__ z, const __half* __restrict__ BC,
    float* __restrict__ out)
{
    __shared__ float2 sdx[CL*NCH];     // 16 KB
    __shared__ float  wtP[4][2][NN];   // per-wave inclusive totals
    __shared__ float  wtG[4][2][NN];

    const int lane = threadIdx.x & 63;
    const int w    = threadIdx.x >> 6;
    const int cmy  = threadIdx.x;            // my chunk (0..255)
    const int row0 = blockIdx.x*2;           // b*DM + d ; row1 = row0+1
    const int b    = (row0 >= DM) ? 1 : 0;
    const int d0   = row0 - b*DM;

    const long base0 = (long)row0*LL;
    const long base1 = base0 + LL;
    const float* gd0 = delta + base0; const float* gx0 = x + base0;
    const float* gd1 = delta + base1; const float* gx1 = x + base1;

    // ---- stage packed (dl,x) for both rows; wave w covers t in [w*512,+512)
    // (wave-local slots only: c = t>>3 in [w*64,+64) -> no barrier needed)
    for (int k=0;k<512;k+=256){
        const int t0 = w*512 + k + lane*4;
        const float4 dv0 = *(const float4*)(gd0 + t0);
        const float4 xv0 = *(const float4*)(gx0 + t0);
        const float4 dv1 = *(const float4*)(gd1 + t0);
        const float4 xv1 = *(const float4*)(gx1 + t0);
        const float dd0[4]={dv0.x,dv0.y,dv0.z,dv0.w}, xx0[4]={xv0.x,xv0.y,xv0.z,xv0.w};
        const float dd1[4]={dv1.x,dv1.y,dv1.z,dv1.w}, xx1[4]={xv1.x,xv1.y,xv1.z,xv1.w};
#pragma unroll
        for (int j=0;j<4;++j){
            const int t = t0 + j, r = t & 7, c = t >> 3;
            float2 wd; wd.x = packdx(dd0[j], xx0[j]); wd.y = packdx(dd1[j], xx1[j]);
            sdx[r*NCH + c] = wd;
        }
    }

    // A rows -> SGPRs (block-uniform). Raw A; LOG2E folded into dl.
    float Ar0[NN], Ar1[NN];
#pragma unroll
    for (int n=0;n<NN;++n){
        Ar0[n] = to_sgpr(A[d0*NN + n]);
        Ar1[n] = to_sgpr(A[(d0+1)*NN + n]);
    }

    // record for (b, r, chunk cmy): BC + b*65536 + r*8192 + cmy*32 (halfs)
    const __half* bc = BC + (long)b*65536 + cmy*32;

    // ---- phase 1: local chunk scan h0=0 -> G (both rows); sum(dl) -> P
    float G0[NN], G1[NN];
#pragma unroll
    for (int n=0;n<NN;++n){ G0[n]=0.f; G1[n]=0.f; }
    float dsl0=0.f, dsl1=0.f;
#pragma unroll 2
    for (int r=0;r<CL;++r){
        const float2 wd = sdx[r*NCH + cmy];
        const float4* rec = (const float4*)(bc + (long)r*8192);
        const float4 rb0 = rec[0], rb1 = rec[1];
        float bb[16];
        unpack8(rb0, bb); unpack8(rb1, bb+8);
        float dl0,x_0,dl1,x_1;
        unpackdx(wd.x, dl0, x_0); unpackdx(wd.y, dl1, x_1);
        dsl0 += dl0; dsl1 += dl1;
        const float dx0 = (dl0*LN2)*x_0, dx1 = (dl1*LN2)*x_1;
#pragma unroll
        for (int n=0;n<NN;++n){
            const float e0 = fexp2(dl0*Ar0[n]);
            G0[n] = __builtin_fmaf(e0, G0[n], bb[n]*dx0);
            const float e1 = fexp2(dl1*Ar1[n]);
            G1[n] = __builtin_fmaf(e1, G1[n], bb[n]*dx1);
        }
    }

    // ---- phase 2: two-level scan (KS within wave, serial compose across 4 waves)
    float h0[NN], h1[NN];
    {
        float P0[NN], P1[NN];
#pragma unroll
        for (int n=0;n<NN;++n){ P0[n]=fexp2(dsl0*Ar0[n]); P1[n]=fexp2(dsl1*Ar1[n]); }
        // inclusive Kogge-Stone within wave
#pragma unroll
        for (int s=1;s<64;s<<=1){
#pragma unroll
            for (int n=0;n<NN;++n){
                const float pl0=__shfl_up(P0[n],s), gl0=__shfl_up(G0[n],s);
                const float pl1=__shfl_up(P1[n],s), gl1=__shfl_up(G1[n],s);
                if (lane >= s){
                    G0[n]=__builtin_fmaf(P0[n],gl0,G0[n]); P0[n]*=pl0;
                    G1[n]=__builtin_fmaf(P1[n],gl1,G1[n]); P1[n]*=pl1;
                }
            }
        }
        // every wave publishes its inclusive total
        if (lane==63){
#pragma unroll
            for (int n=0;n<NN;++n){
                wtP[w][0][n]=P0[n]; wtG[w][0][n]=G0[n];
                wtP[w][1][n]=P1[n]; wtG[w][1][n]=G1[n];
            }
        }
        __syncthreads();
        // exclusive within wave, then compose with prefix of preceding waves
#pragma unroll
        for (int n=0;n<NN;++n){
            const float pe0=__shfl_up(P0[n],1), ge0=__shfl_up(G0[n],1);
            const float pe1=__shfl_up(P1[n],1), ge1=__shfl_up(G1[n],1);
            const float Px0 = (lane==0)?1.f:pe0, Gx0 = (lane==0)?0.f:ge0;
            const float Px1 = (lane==0)?1.f:pe1, Gx1 = (lane==0)?0.f:ge1;
            float gp0 = 0.f, gp1 = 0.f;
            for (int wv=0; wv<w; ++wv){          // wave-uniform trip count
                gp0 = __builtin_fmaf(wtP[wv][0][n], gp0, wtG[wv][0][n]);
                gp1 = __builtin_fmaf(wtP[wv][1][n], gp1, wtG[wv][1][n]);
            }
            h0[n] = __builtin_fmaf(Px0, gp0, Gx0);
            h1[n] = __builtin_fmaf(Px1, gp1, Gx1);
        }
    }

    // ---- phase 3: re-scan with true h_start; stash fp32 {y+xD} in the slot.
    // unroll 1 + prefetch of the RAW packed next record + next wd: one
    // unpacked fp32 set live at a time (vs R0's unroll-2 two sets).
    const float Dd0 = to_sgpr(Dv[d0]), Dd1 = to_sgpr(Dv[d0+1]);
    {
        float4 rb0 = ((const float4*)bc)[0];
        float4 rb1 = ((const float4*)bc)[1];
        float4 rc0 = ((const float4*)bc)[2];
        float4 rc1 = ((const float4*)bc)[3];
        float2 wdc = sdx[cmy];
#pragma unroll 1
        for (int r=0;r<CL;++r){
            const int rn = (r<CL-1) ? r+1 : r;
            const float4* nrec = (const float4*)(bc + (long)rn*8192);
            const float4 nb0 = nrec[0], nb1 = nrec[1];
            const float4 nc0 = nrec[2], nc1 = nrec[3];
            const float2 nwd = sdx[rn*NCH + cmy];   // read-before-write ok at r=7

            float bb[16], cc[16];
            unpack8(rb0, bb); unpack8(rb1, bb+8);
            unpack8(rc0, cc); unpack8(rc1, cc+8);
            float dl0,x_0,dl1,x_1;
            unpackdx(wdc.x, dl0, x_0); unpackdx(wdc.y, dl1, x_1);
            const float dx0 = (dl0*LN2)*x_0, dx1 = (dl1*LN2)*x_1;
            float ya0=0.f, yb0=0.f, ya1=0.f, yb1=0.f;
#pragma unroll
            for (int n=0;n<NN;n+=2){
                const float e0a = fexp2(dl0*Ar0[n]);
                h0[n]  =__builtin_fmaf(e0a,h0[n],  bb[n]*dx0);   ya0=__builtin_fmaf(h0[n],  cc[n],  ya0);
                const float e0b = fexp2(dl0*Ar0[n+1]);
                h0[n+1]=__builtin_fmaf(e0b,h0[n+1],bb[n+1]*dx0); yb0=__builtin_fmaf(h0[n+1],cc[n+1],yb0);
                const float e1a = fexp2(dl1*Ar1[n]);
                h1[n]  =__builtin_fmaf(e1a,h1[n],  bb[n]*dx1);   ya1=__builtin_fmaf(h1[n],  cc[n],  ya1);
                const float e1b = fexp2(dl1*Ar1[n+1]);
                h1[n+1]=__builtin_fmaf(e1b,h1[n+1],bb[n+1]*dx1); yb1=__builtin_fmaf(h1[n+1],cc[n+1],yb1);
            }
            float2 yo;
            yo.x = __builtin_fmaf(x_0, Dd0, ya0+yb0);
            yo.y = __builtin_fmaf(x_1, Dd1, ya1+yb1);
            sdx[r*NCH + cmy] = yo;              // same-wave slot, no barrier
            rb0=nb0; rb1=nb1; rc0=nc0; rc1=nc1; wdc=nwd;
        }
    }

    // ---- epilogue: stream z once, coalesced float4 in/out (same-wave slots)
    const float* gz0 = z + base0; const float* gz1 = z + base1;
    float* go0 = out + base0;     float* go1 = out + base1;
    for (int k=0;k<512;k+=256){
        const int t0 = w*512 + k + lane*4;
        const float4 zv0 = *(const float4*)(gz0 + t0);
        const float4 zv1 = *(const float4*)(gz1 + t0);
        const float zz0[4]={zv0.x,zv0.y,zv0.z,zv0.w}, zz1[4]={zv1.x,zv1.y,zv1.z,zv1.w};
        float o0[4], o1[4];
#pragma unroll
        for (int j=0;j<4;++j){
            const int t = t0 + j, r = t & 7, c = t >> 3;
            const float2 wd = sdx[r*NCH + c];
            const float s0 = frcp(1.f + fexp2(-zz0[j]*LOG2E));
            const float s1 = frcp(1.f + fexp2(-zz1[j]*LOG2E));
            o0[j] = wd.x * (zz0[j]*s0);
            o1[j] = wd.y * (zz1[j]*s1);
        }
        float4 a  = {o0[0],o0[1],o0[2],o0[3]};
        float4 bq = {o1[0],o1[1],o1[2],o1[3]};
        *(float4*)(go0 + t0) = a;
        *(float4*)(go1 + t0) = bq;
    }
}

extern "C" void kernel_launch(void* const* d_in, const int* in_sizes, int n_in,
                              void* d_out, int out_size, void* d_ws, size_t ws_size,
                              hipStream_t stream) {
    const float* x     = (const float*)d_in[0];
    const float* delta = (const float*)d_in[1];
    const float* A     = (const float*)d_in[2];
    const float* B     = (const float*)d_in[3];
    const float* C     = (const float*)d_in[4];
    const float* Dv    = (const float*)d_in[5];
    const float* z     = (const float*)d_in[6];
    float* out = (float*)d_out;

    __half* BC = (__half*)d_ws;               // 131072 halfs = 256 KB

    transpose_bc<<<dim3(64), dim3(256), 0, stream>>>(B, C, BC);
    ssm_scan<<<dim3(DM), dim3(256), 0, stream>>>(x, delta, A, Dv, z, BC, out);
}

// Round 6
// 162.166 us; speedup vs baseline: 1.3203x; 1.0025x over previous
//
#include <hip/hip_runtime.h>
#include <hip/hip_fp16.h>

#define LOG2E 1.44269504088896340736f
#define LN2   0.69314718055994530942f
#define DM 1536
#define LL  2048
#define NN  16
#define NCH 128    // chunks per row (2 waves x 64 lanes)
#define CL  16     // steps per chunk = LL / NCH

__device__ __forceinline__ float fexp2(float v){ return __builtin_amdgcn_exp2f(v); }
__device__ __forceinline__ float frcp(float v){ return __builtin_amdgcn_rcpf(v); }

// pack {d*LOG2E, x} as half2 in a float. exp2 args use dl*A_raw (A in SGPRs);
// dx is recovered as (dl*LN2)*x so x stays available for the x*D term.
__device__ __forceinline__ float packdx(float d, float x){
    return __builtin_bit_cast(float, __floats2half2_rn(d*LOG2E, x));
}
__device__ __forceinline__ void unpackdx(float f, float& dl, float& x){
    const float2 p = __half22float2(__builtin_bit_cast(__half2, f));
    dl = p.x; x = p.y;
}
// float4 = 8 packed halfs -> 8 floats
__device__ __forceinline__ void unpack8(const float4 f, float* o){
    float2 p;
    p = __half22float2(__builtin_bit_cast(__half2, f.x)); o[0]=p.x; o[1]=p.y;
    p = __half22float2(__builtin_bit_cast(__half2, f.y)); o[2]=p.x; o[3]=p.y;
    p = __half22float2(__builtin_bit_cast(__half2, f.z)); o[4]=p.x; o[5]=p.y;
    p = __half22float2(__builtin_bit_cast(__half2, f.w)); o[6]=p.x; o[7]=p.y;
}
// force a block-uniform float into an SGPR
__device__ __forceinline__ float to_sgpr(float v){
    return __builtin_bit_cast(float, __builtin_amdgcn_readfirstlane(__builtin_bit_cast(int, v)));
}

// B,C fp32 [b][n][t] -> fp16 records: BC[((b*16 + (t&15))*128 + (t>>4))*32 + n]
// (B at +n, C at +16+n). Per (step r, chunk c) one contiguous 64 B record;
// per r the 128 chunks form one 8 KB slab read coalesced by 2 waves.
__global__ __launch_bounds__(256) void transpose_bc(
        const float* __restrict__ Bm, const float* __restrict__ Cm,
        __half* __restrict__ BC){
    const int q  = blockIdx.x*256 + threadIdx.x;   // 16384 float4 quads
    const int t0 = (q & 511) << 2;
    const int n  = (q >> 9) & 15;
    const int b  = q >> 13;
    const long i = (long)(b*NN + n)*LL + t0;
    const float4 bv = *(const float4*)(Bm + i);
    const float4 cv = *(const float4*)(Cm + i);
    const float bb[4]={bv.x,bv.y,bv.z,bv.w}, cc[4]={cv.x,cv.y,cv.z,cv.w};
#pragma unroll
    for (int j=0;j<4;++j){
        const int t = t0 + j;
        const long o = ((long)((b*CL + (t&15))*NCH + (t>>4)))*32 + n;
        BC[o]      = __float2half_rn(bb[j]);
        BC[o + 16] = __float2half_rn(cc[j]);
    }
}

// Block = 2 waves = ONE row-pair (2 consecutive d, same b). CL=16 / 2-wave is
// the busy-work-optimal config from the cross-round ledger: chip-wide
// phase-1/3 work is CL-invariant but KS-scan/compose work scales with thread
// count (CL8/4w measured +25% VALU-busy vs this shape). Register diet from
// R5 so it fits 128 VGPR (R0 needed 168 -> only 3 waves/SIMD):
//  - A rows in SGPRs via readfirstlane.
//  - phase 3 unroll 1 + prefetch of RAW packed record (16 regs, not two
//    unpacked fp32 sets).
//  - {d*LOG2E, x} packed half2 in LDS; dx = (dl*LN2)*x recovered in-loop.
// Occupancy: grid 1536 x 2 waves = 12 waves/CU supply; VGPR cap at 128 is
// 16/CU -> ALL 6 blocks/CU resident, steady (no 4+2 block wobble like R5).
// LDS 16.5 KB. Phase 3 stashes fp32 {y+xD} back into the same-wave slot.
__global__ __launch_bounds__(128, 4) void ssm_scan(
    const float* __restrict__ x, const float* __restrict__ delta,
    const float* __restrict__ A, const float* __restrict__ Dv,
    const float* __restrict__ z, const __half* __restrict__ BC,
    float* __restrict__ out)
{
    __shared__ float2 sdx[CL*NCH];     // 16 KB
    __shared__ float  wtot[2][2][NN];  // [P/G][row][n] from wave 0 lane 63

    const int lane = threadIdx.x & 63;
    const int w    = threadIdx.x >> 6;
    const int cmy  = threadIdx.x;            // my chunk (0..127)
    const int row0 = blockIdx.x*2;           // b*DM + d ; row1 = row0+1
    const int b    = (row0 >= DM) ? 1 : 0;
    const int d0   = row0 - b*DM;

    const long base0 = (long)row0*LL;
    const long base1 = base0 + LL;
    const float* gd0 = delta + base0; const float* gx0 = x + base0;
    const float* gd1 = delta + base1; const float* gx1 = x + base1;

    // ---- stage packed (dl,x) for both rows; wave w covers t in [w*1024,+1024)
    // (wave-local slots: c = t>>4 in [w*64,+64) -> no barrier needed)
    for (int k=0;k<1024;k+=256){
        const int t0 = w*1024 + k + lane*4;
        const float4 dv0 = *(const float4*)(gd0 + t0);
        const float4 xv0 = *(const float4*)(gx0 + t0);
        const float4 dv1 = *(const float4*)(gd1 + t0);
        const float4 xv1 = *(const float4*)(gx1 + t0);
        const float dd0[4]={dv0.x,dv0.y,dv0.z,dv0.w}, xx0[4]={xv0.x,xv0.y,xv0.z,xv0.w};
        const float dd1[4]={dv1.x,dv1.y,dv1.z,dv1.w}, xx1[4]={xv1.x,xv1.y,xv1.z,xv1.w};
#pragma unroll
        for (int j=0;j<4;++j){
            const int t = t0 + j, r = t & 15, c = t >> 4;
            float2 wd; wd.x = packdx(dd0[j], xx0[j]); wd.y = packdx(dd1[j], xx1[j]);
            sdx[r*NCH + c] = wd;
        }
    }

    // A rows -> SGPRs (block-uniform). Raw A; LOG2E folded into dl.
    float Ar0[NN], Ar1[NN];
#pragma unroll
    for (int n=0;n<NN;++n){
        Ar0[n] = to_sgpr(A[d0*NN + n]);
        Ar1[n] = to_sgpr(A[(d0+1)*NN + n]);
    }

    // record for (b, r, chunk cmy): BC + b*65536 + r*4096 + cmy*32 (halfs)
    const __half* bc = BC + (long)b*65536 + cmy*32;

    // ---- phase 1: local chunk scan h0=0 -> G (both rows); sum(dl) -> P
    float G0[NN], G1[NN];
#pragma unroll
    for (int n=0;n<NN;++n){ G0[n]=0.f; G1[n]=0.f; }
    float dsl0=0.f, dsl1=0.f;
#pragma unroll 2
    for (int r=0;r<CL;++r){
        const float2 wd = sdx[r*NCH + cmy];
        const float4* rec = (const float4*)(bc + (long)r*4096);
        const float4 rb0 = rec[0], rb1 = rec[1];
        float bb[16];
        unpack8(rb0, bb); unpack8(rb1, bb+8);
        float dl0,x_0,dl1,x_1;
        unpackdx(wd.x, dl0, x_0); unpackdx(wd.y, dl1, x_1);
        dsl0 += dl0; dsl1 += dl1;
        const float dx0 = (dl0*LN2)*x_0, dx1 = (dl1*LN2)*x_1;
#pragma unroll
        for (int n=0;n<NN;++n){
            const float e0 = fexp2(dl0*Ar0[n]);
            G0[n] = __builtin_fmaf(e0, G0[n], bb[n]*dx0);
            const float e1 = fexp2(dl1*Ar1[n]);
            G1[n] = __builtin_fmaf(e1, G1[n], bb[n]*dx1);
        }
    }

    // ---- phase 2: two-level scan (KS within wave, wave-0 totals -> wave 1)
    float h0[NN], h1[NN];
    {
        float P0[NN], P1[NN];
#pragma unroll
        for (int n=0;n<NN;++n){ P0[n]=fexp2(dsl0*Ar0[n]); P1[n]=fexp2(dsl1*Ar1[n]); }
        // inclusive Kogge-Stone within wave
#pragma unroll
        for (int s=1;s<64;s<<=1){
#pragma unroll
            for (int n=0;n<NN;++n){
                const float pl0=__shfl_up(P0[n],s), gl0=__shfl_up(G0[n],s);
                const float pl1=__shfl_up(P1[n],s), gl1=__shfl_up(G1[n],s);
                if (lane >= s){
                    G0[n]=__builtin_fmaf(P0[n],gl0,G0[n]); P0[n]*=pl0;
                    G1[n]=__builtin_fmaf(P1[n],gl1,G1[n]); P1[n]*=pl1;
                }
            }
        }
        // wave-0 totals -> LDS
        if (w==0 && lane==63){
#pragma unroll
            for (int n=0;n<NN;++n){
                wtot[0][0][n]=P0[n]; wtot[1][0][n]=G0[n];
                wtot[0][1][n]=P1[n]; wtot[1][1][n]=G1[n];
            }
        }
        __syncthreads();
        // exclusive within wave, then compose with wave-0 total (wave 1 only)
#pragma unroll
        for (int n=0;n<NN;++n){
            const float pe0=__shfl_up(P0[n],1), ge0=__shfl_up(G0[n],1);
            const float pe1=__shfl_up(P1[n],1), ge1=__shfl_up(G1[n],1);
            const float Px0 = (lane==0)?1.f:pe0, Gx0 = (lane==0)?0.f:ge0;
            const float Px1 = (lane==0)?1.f:pe1, Gx1 = (lane==0)?0.f:ge1;
            const float Gt0 = (w==0)?0.f:wtot[1][0][n];
            const float Gt1 = (w==0)?0.f:wtot[1][1][n];
            h0[n] = __builtin_fmaf(Px0, Gt0, Gx0);
            h1[n] = __builtin_fmaf(Px1, Gt1, Gx1);
        }
    }

    // ---- phase 3: re-scan with true h_start; stash fp32 {y+xD} in the slot.
    // unroll 1 + prefetch of the RAW packed next record + next wd: one
    // unpacked fp32 set live at a time.
    const float Dd0 = to_sgpr(Dv[d0]), Dd1 = to_sgpr(Dv[d0+1]);
    {
        float4 rb0 = ((const float4*)bc)[0];
        float4 rb1 = ((const float4*)bc)[1];
        float4 rc0 = ((const float4*)bc)[2];
        float4 rc1 = ((const float4*)bc)[3];
        float2 wdc = sdx[cmy];
#pragma unroll 1
        for (int r=0;r<CL;++r){
            const int rn = (r<CL-1) ? r+1 : r;
            const float4* nrec = (const float4*)(bc + (long)rn*4096);
            const float4 nb0 = nrec[0], nb1 = nrec[1];
            const float4 nc0 = nrec[2], nc1 = nrec[3];
            const float2 nwd = sdx[rn*NCH + cmy];   // read-before-write ok at r=15

            float bb[16], cc[16];
            unpack8(rb0, bb); unpack8(rb1, bb+8);
            unpack8(rc0, cc); unpack8(rc1, cc+8);
            float dl0,x_0,dl1,x_1;
            unpackdx(wdc.x, dl0, x_0); unpackdx(wdc.y, dl1, x_1);
            const float dx0 = (dl0*LN2)*x_0, dx1 = (dl1*LN2)*x_1;
            float ya0=0.f, yb0=0.f, ya1=0.f, yb1=0.f;
#pragma unroll
            for (int n=0;n<NN;n+=2){
                const float e0a = fexp2(dl0*Ar0[n]);
                h0[n]  =__builtin_fmaf(e0a,h0[n],  bb[n]*dx0);   ya0=__builtin_fmaf(h0[n],  cc[n],  ya0);
                const float e0b = fexp2(dl0*Ar0[n+1]);
                h0[n+1]=__builtin_fmaf(e0b,h0[n+1],bb[n+1]*dx0); yb0=__builtin_fmaf(h0[n+1],cc[n+1],yb0);
                const float e1a = fexp2(dl1*Ar1[n]);
                h1[n]  =__builtin_fmaf(e1a,h1[n],  bb[n]*dx1);   ya1=__builtin_fmaf(h1[n],  cc[n],  ya1);
                const float e1b = fexp2(dl1*Ar1[n+1]);
                h1[n+1]=__builtin_fmaf(e1b,h1[n+1],bb[n+1]*dx1); yb1=__builtin_fmaf(h1[n+1],cc[n+1],yb1);
            }
            float2 yo;
            yo.x = __builtin_fmaf(x_0, Dd0, ya0+yb0);
            yo.y = __builtin_fmaf(x_1, Dd1, ya1+yb1);
            sdx[r*NCH + cmy] = yo;              // same-wave slot, no barrier
            rb0=nb0; rb1=nb1; rc0=nc0; rc1=nc1; wdc=nwd;
        }
    }

    // ---- epilogue: stream z once, coalesced float4 in/out (same-wave slots)
    const float* gz0 = z + base0; const float* gz1 = z + base1;
    float* go0 = out + base0;     float* go1 = out + base1;
    for (int k=0;k<1024;k+=256){
        const int t0 = w*1024 + k + lane*4;
        const float4 zv0 = *(const float4*)(gz0 + t0);
        const float4 zv1 = *(const float4*)(gz1 + t0);
        const float zz0[4]={zv0.x,zv0.y,zv0.z,zv0.w}, zz1[4]={zv1.x,zv1.y,zv1.z,zv1.w};
        float o0[4], o1[4];
#pragma unroll
        for (int j=0;j<4;++j){
            const int t = t0 + j, r = t & 15, c = t >> 4;
            const float2 wd = sdx[r*NCH + c];
            const float s0 = frcp(1.f + fexp2(-zz0[j]*LOG2E));
            const float s1 = frcp(1.f + fexp2(-zz1[j]*LOG2E));
            o0[j] = wd.x * (zz0[j]*s0);
            o1[j] = wd.y * (zz1[j]*s1);
        }
        float4 a  = {o0[0],o0[1],o0[2],o0[3]};
        float4 bq = {o1[0],o1[1],o1[2],o1[3]};
        *(float4*)(go0 + t0) = a;
        *(float4*)(go1 + t0) = bq;
    }
}

extern "C" void kernel_launch(void* const* d_in, const int* in_sizes, int n_in,
                              void* d_out, int out_size, void* d_ws, size_t ws_size,
                              hipStream_t stream) {
    const float* x     = (const float*)d_in[0];
    const float* delta = (const float*)d_in[1];
    const float* A     = (const float*)d_in[2];
    const float* B     = (const float*)d_in[3];
    const float* C     = (const float*)d_in[4];
    const float* Dv    = (const float*)d_in[5];
    const float* z     = (const float*)d_in[6];
    float* out = (float*)d_out;

    __half* BC = (__half*)d_ws;               // 131072 halfs = 256 KB

    transpose_bc<<<dim3(64), dim3(256), 0, stream>>>(B, C, BC);
    ssm_scan<<<dim3(DM), dim3(128), 0, stream>>>(x, delta, A, Dv, z, BC, out);
}

// Round 7
// 158.204 us; speedup vs baseline: 1.3534x; 1.0250x over previous
//
#include <hip/hip_runtime.h>
#include <hip/hip_fp16.h>

#define LOG2E 1.44269504088896340736f
#define DM 1536
#define LL  2048
#define NN  16
#define NCH 128    // chunks per row (2 waves x 64 lanes)
#define CL  16     // steps per chunk = LL / NCH

__device__ __forceinline__ float fexp2(float v){ return __builtin_amdgcn_exp2f(v); }
__device__ __forceinline__ float frcp(float v){ return __builtin_amdgcn_rcpf(v); }

// pack {d, x} as half2 in a float (R0 format: raw d, raw x)
__device__ __forceinline__ float packdx(float d, float x){
    return __builtin_bit_cast(float, __floats2half2_rn(d, x));
}
__device__ __forceinline__ void unpackdx(float f, float& d, float& x){
    const float2 p = __half22float2(__builtin_bit_cast(__half2, f));
    d = p.x; x = p.y;
}
// float4 = 8 packed halfs -> 8 floats
__device__ __forceinline__ void unpack8(const float4 f, float* o){
    float2 p;
    p = __half22float2(__builtin_bit_cast(__half2, f.x)); o[0]=p.x; o[1]=p.y;
    p = __half22float2(__builtin_bit_cast(__half2, f.y)); o[2]=p.x; o[3]=p.y;
    p = __half22float2(__builtin_bit_cast(__half2, f.z)); o[4]=p.x; o[5]=p.y;
    p = __half22float2(__builtin_bit_cast(__half2, f.w)); o[6]=p.x; o[7]=p.y;
}
// force a block-uniform float into an SGPR
__device__ __forceinline__ float to_sgpr(float v){
    return __builtin_bit_cast(float, __builtin_amdgcn_readfirstlane(__builtin_bit_cast(int, v)));
}

// B,C fp32 [b][n][t] -> fp16 records: BC[((b*16 + (t&15))*128 + (t>>4))*32 + n]
// (B at +n, C at +16+n). Per (step r, chunk c) one contiguous 64 B record;
// per r the 128 chunks form one 8 KB slab read coalesced by 2 waves.
__global__ __launch_bounds__(256) void transpose_bc(
        const float* __restrict__ Bm, const float* __restrict__ Cm,
        __half* __restrict__ BC){
    const int q  = blockIdx.x*256 + threadIdx.x;   // 16384 float4 quads
    const int t0 = (q & 511) << 2;
    const int n  = (q >> 9) & 15;
    const int b  = q >> 13;
    const long i = (long)(b*NN + n)*LL + t0;
    const float4 bv = *(const float4*)(Bm + i);
    const float4 cv = *(const float4*)(Cm + i);
    const float bb[4]={bv.x,bv.y,bv.z,bv.w}, cc[4]={cv.x,cv.y,cv.z,cv.w};
#pragma unroll
    for (int j=0;j<4;++j){
        const int t = t0 + j;
        const long o = ((long)((b*CL + (t&15))*NCH + (t>>4)))*32 + n;
        BC[o]      = __float2half_rn(bb[j]);
        BC[o + 16] = __float2half_rn(cc[j]);
    }
}

// Block = 2 waves = ONE row-pair (2 consecutive d, same b) — the R0 structure
// (cross-round ledger: CL16/2w is the busy-work floor, ~32 µs chip-wide issue;
// CL8 variants pay +25% KS-scan work; occupancy supply is fixed at 12
// waves/CU by thread count, so sub-128-VGPR diets buy nothing).
// Changes vs R0, each strictly positive:
//  - A rows (pre-multiplied by LOG2E) and D in SGPRs via readfirstlane:
//    -32 VGPR of array pressure (168 -> ~136), fewer VALU ops, no downside.
//  - everything else IS R0: XOR-swizzled slot(r,c) = r*128 + (c^r) (R6
//    dropped it -> 12x bank conflicts: r*256 = 0 mod 32 banks, so stage
//    writes / epilogue reads where r varies per-lane collide 4-way; c^r
//    spreads them across banks), unroll-2 phase 1/3 (proven pipelining),
//    raw {d,x} fp16 packing, fp32 {y0,y1} stash, coalesced epilogue.
// LDS 16.5 KB. Grid 1536 x 2 waves = 12 waves/CU, all resident at (128,3).
__global__ __launch_bounds__(128, 3) void ssm_scan(
    const float* __restrict__ x, const float* __restrict__ delta,
    const float* __restrict__ A, const float* __restrict__ Dv,
    const float* __restrict__ z, const __half* __restrict__ BC,
    float* __restrict__ out)
{
    __shared__ float2 sdx[CL*NCH];     // 16 KB
    __shared__ float  wtot[2][2][NN];  // [P/G][row][n] from wave 0 lane 63

    const int lane = threadIdx.x & 63;
    const int w    = threadIdx.x >> 6;
    const int row0 = blockIdx.x*2;           // b*DM + d ; row1 = row0+1
    const int b    = (row0 >= DM) ? 1 : 0;
    const int d0   = row0 - b*DM;
    const int cmy  = w*64 + lane;            // my chunk (0..127)

    const long base0 = (long)row0*LL;
    const long base1 = base0 + LL;
    const float* gd0 = delta + base0; const float* gx0 = x + base0;
    const float* gd1 = delta + base1; const float* gx1 = x + base1;

    // ---- stage packed (d,x) for both rows; wave w covers t in [w*1024, +1024)
    for (int k=0;k<1024;k+=256){
        const int t0 = w*1024 + k + lane*4;
        const float4 dv0 = *(const float4*)(gd0 + t0);
        const float4 xv0 = *(const float4*)(gx0 + t0);
        const float4 dv1 = *(const float4*)(gd1 + t0);
        const float4 xv1 = *(const float4*)(gx1 + t0);
        const float dd0[4]={dv0.x,dv0.y,dv0.z,dv0.w}, xx0[4]={xv0.x,xv0.y,xv0.z,xv0.w};
        const float dd1[4]={dv1.x,dv1.y,dv1.z,dv1.w}, xx1[4]={xv1.x,xv1.y,xv1.z,xv1.w};
#pragma unroll
        for (int j=0;j<4;++j){
            const int t = t0 + j, r = t & 15, c = t >> 4;
            float2 wd; wd.x = packdx(dd0[j], xx0[j]); wd.y = packdx(dd1[j], xx1[j]);
            sdx[r*NCH + (c^r)] = wd;
        }
    }

    // A rows (x LOG2E) -> SGPRs (block-uniform): no VGPR arrays, no per-step
    // LOG2E muls. D likewise.
    float A20[NN], A21[NN];
#pragma unroll
    for (int n=0;n<NN;++n){
        A20[n] = to_sgpr(A[d0*NN+n]     * LOG2E);
        A21[n] = to_sgpr(A[(d0+1)*NN+n] * LOG2E);
    }

    // record for (b, r, chunk cmy): BC + b*65536 + r*4096 + cmy*32 (halfs)
    const __half* bc = BC + (long)b*65536 + cmy*32;

    // ---- phase 1: local chunk scan h0=0 -> G (both rows); dsum -> P
    float G0[NN], G1[NN];
#pragma unroll
    for (int n=0;n<NN;++n){ G0[n]=0.f; G1[n]=0.f; }
    float ds0=0.f, ds1=0.f;
#pragma unroll 2
    for (int r=0;r<CL;++r){
        const float2 wd = sdx[r*NCH + (cmy^r)];
        const float4* rec = (const float4*)(bc + (long)r*4096);
        float bb[16];
        unpack8(rec[0], bb); unpack8(rec[1], bb+8);
        float d_0,x_0,d_1,x_1;
        unpackdx(wd.x, d_0, x_0); unpackdx(wd.y, d_1, x_1);
        ds0 += d_0; ds1 += d_1;
        const float dx0 = d_0*x_0, dx1 = d_1*x_1;
#pragma unroll
        for (int n=0;n<NN;++n){
            const float e0 = fexp2(d_0*A20[n]);
            G0[n] = __builtin_fmaf(e0, G0[n], bb[n]*dx0);
            const float e1 = fexp2(d_1*A21[n]);
            G1[n] = __builtin_fmaf(e1, G1[n], bb[n]*dx1);
        }
    }

    // ---- phase 2: two-level scan
    float h0[NN], h1[NN];
    {
        float P0[NN], P1[NN];
#pragma unroll
        for (int n=0;n<NN;++n){ P0[n]=fexp2(ds0*A20[n]); P1[n]=fexp2(ds1*A21[n]); }
        // inclusive Kogge-Stone within wave
#pragma unroll
        for (int s=1;s<64;s<<=1){
#pragma unroll
            for (int n=0;n<NN;++n){
                const float pl0=__shfl_up(P0[n],s), gl0=__shfl_up(G0[n],s);
                const float pl1=__shfl_up(P1[n],s), gl1=__shfl_up(G1[n],s);
                if (lane >= s){
                    G0[n]=__builtin_fmaf(P0[n],gl0,G0[n]); P0[n]*=pl0;
                    G1[n]=__builtin_fmaf(P1[n],gl1,G1[n]); P1[n]*=pl1;
                }
            }
        }
        // wave-0 totals -> LDS
        if (w==0 && lane==63){
#pragma unroll
            for (int n=0;n<NN;++n){
                wtot[0][0][n]=P0[n]; wtot[1][0][n]=G0[n];
                wtot[0][1][n]=P1[n]; wtot[1][1][n]=G1[n];
            }
        }
        __syncthreads();
        // exclusive within wave, then compose with wave-0 total (wave 1 only)
#pragma unroll
        for (int n=0;n<NN;++n){
            const float pe0=__shfl_up(P0[n],1), ge0=__shfl_up(G0[n],1);
            const float pe1=__shfl_up(P1[n],1), ge1=__shfl_up(G1[n],1);
            const float Px0 = (lane==0)?1.f:pe0, Gx0 = (lane==0)?0.f:ge0;
            const float Px1 = (lane==0)?1.f:pe1, Gx1 = (lane==0)?0.f:ge1;
            const float Gt0 = (w==0)?0.f:wtot[1][0][n];
            const float Gt1 = (w==0)?0.f:wtot[1][1][n];
            h0[n] = __builtin_fmaf(Px0, Gt0, Gx0);
            h1[n] = __builtin_fmaf(Px1, Gt1, Gx1);
        }
    }

    // ---- phase 3: re-scan with true h_start; stash fp32 {y0+x0*D0, y1+x1*D1}
    const float Dd0 = to_sgpr(Dv[d0]), Dd1 = to_sgpr(Dv[d0+1]);
#pragma unroll 2
    for (int r=0;r<CL;++r){
        const int slot = r*NCH + (cmy^r);
        const float2 wd = sdx[slot];
        const float4* rec = (const float4*)(bc + (long)r*4096);
        float bb[16], cc[16];
        unpack8(rec[0], bb); unpack8(rec[1], bb+8);
        unpack8(rec[2], cc); unpack8(rec[3], cc+8);
        float d_0,x_0,d_1,x_1;
        unpackdx(wd.x, d_0, x_0); unpackdx(wd.y, d_1, x_1);
        const float dx0 = d_0*x_0, dx1 = d_1*x_1;
        float ya0=0.f, yb0=0.f, ya1=0.f, yb1=0.f;
#pragma unroll
        for (int n=0;n<NN;n+=2){
            const float e0a = fexp2(d_0*A20[n]);
            h0[n]  =__builtin_fmaf(e0a,h0[n],  bb[n]*dx0);   ya0=__builtin_fmaf(h0[n],  cc[n],  ya0);
            const float e0b = fexp2(d_0*A20[n+1]);
            h0[n+1]=__builtin_fmaf(e0b,h0[n+1],bb[n+1]*dx0); yb0=__builtin_fmaf(h0[n+1],cc[n+1],yb0);
            const float e1a = fexp2(d_1*A21[n]);
            h1[n]  =__builtin_fmaf(e1a,h1[n],  bb[n]*dx1);   ya1=__builtin_fmaf(h1[n],  cc[n],  ya1);
            const float e1b = fexp2(d_1*A21[n+1]);
            h1[n+1]=__builtin_fmaf(e1b,h1[n+1],bb[n+1]*dx1); yb1=__builtin_fmaf(h1[n+1],cc[n+1],yb1);
        }
        float2 yo;
        yo.x = __builtin_fmaf(x_0, Dd0, ya0+yb0);
        yo.y = __builtin_fmaf(x_1, Dd1, ya1+yb1);
        sdx[slot] = yo;                        // silu applied in epilogue
    }

    // ---- epilogue: stream z once per row, coalesced float4 in/out
    const float* gz0 = z + base0; const float* gz1 = z + base1;
    float* go0 = out + base0;     float* go1 = out + base1;
    for (int k=0;k<1024;k+=256){
        const int t0 = w*1024 + k + lane*4;
        const float4 zv0 = *(const float4*)(gz0 + t0);
        const float4 zv1 = *(const float4*)(gz1 + t0);
        const float zz0[4]={zv0.x,zv0.y,zv0.z,zv0.w}, zz1[4]={zv1.x,zv1.y,zv1.z,zv1.w};
        float o0[4], o1[4];
#pragma unroll
        for (int j=0;j<4;++j){
            const int t = t0 + j, r = t & 15, c = t >> 4;
            const float2 wd = sdx[r*NCH + (c^r)];
            const float s0 = frcp(1.f + fexp2(-zz0[j]*LOG2E));
            const float s1 = frcp(1.f + fexp2(-zz1[j]*LOG2E));
            o0[j] = wd.x * (zz0[j]*s0);
            o1[j] = wd.y * (zz1[j]*s1);
        }
        float4 a  = {o0[0],o0[1],o0[2],o0[3]};
        float4 bq = {o1[0],o1[1],o1[2],o1[3]};
        *(float4*)(go0 + t0) = a;
        *(float4*)(go1 + t0) = bq;
    }
}

extern "C" void kernel_launch(void* const* d_in, const int* in_sizes, int n_in,
                              void* d_out, int out_size, void* d_ws, size_t ws_size,
                              hipStream_t stream) {
    const float* x     = (const float*)d_in[0];
    const float* delta = (const float*)d_in[1];
    const float* A     = (const float*)d_in[2];
    const float* B     = (const float*)d_in[3];
    const float* C     = (const float*)d_in[4];
    const float* Dv    = (const float*)d_in[5];
    const float* z     = (const float*)d_in[6];
    float* out = (float*)d_out;

    __half* BC = (__half*)d_ws;               // 131072 halfs = 256 KB

    transpose_bc<<<dim3(64), dim3(256), 0, stream>>>(B, C, BC);
    ssm_scan<<<dim3(DM), dim3(128), 0, stream>>>(x, delta, A, Dv, z, BC, out);
}

// Round 8
// 155.456 us; speedup vs baseline: 1.3773x; 1.0177x over previous
//
#include <hip/hip_runtime.h>
#include <hip/hip_fp16.h>

#define LOG2E 1.44269504088896340736f
#define DM 1536
#define LL  2048
#define NN  16
#define NCH 128    // chunks per row (2 waves x 64 lanes)
#define CL  16     // steps per chunk = LL / NCH

__device__ __forceinline__ float fexp2(float v){ return __builtin_amdgcn_exp2f(v); }
__device__ __forceinline__ float frcp(float v){ return __builtin_amdgcn_rcpf(v); }

// pack {d, x} as half2 in a float
__device__ __forceinline__ float packdx(float d, float x){
    return __builtin_bit_cast(float, __floats2half2_rn(d, x));
}
__device__ __forceinline__ void unpackdx(float f, float& d, float& x){
    const float2 p = __half22float2(__builtin_bit_cast(__half2, f));
    d = p.x; x = p.y;
}
// float4 = 8 packed halfs -> 8 floats
__device__ __forceinline__ void unpack8(const float4 f, float* o){
    float2 p;
    p = __half22float2(__builtin_bit_cast(__half2, f.x)); o[0]=p.x; o[1]=p.y;
    p = __half22float2(__builtin_bit_cast(__half2, f.y)); o[2]=p.x; o[3]=p.y;
    p = __half22float2(__builtin_bit_cast(__half2, f.z)); o[4]=p.x; o[5]=p.y;
    p = __half22float2(__builtin_bit_cast(__half2, f.w)); o[6]=p.x; o[7]=p.y;
}
// force a block-uniform float into an SGPR
__device__ __forceinline__ float to_sgpr(float v){
    return __builtin_bit_cast(float, __builtin_amdgcn_readfirstlane(__builtin_bit_cast(int, v)));
}

// B,C fp32 [b][n][t] -> fp16 records (layout IDENTICAL to before):
//   record rec=(b*16+r)*128+c holds halfs [B n=0..15 | C n=0..15], t = c*16+r.
// REWRITE (R8): the old kernel wrote 8 scattered 2-byte stores/thread (~131K
// serialized write transactions -> est. ~65-75 us, half the wall time!).
// Now: thread u = one 16B QUARTER-record (8 halfs of B or C): 8 stride-8KB
// dword gathers (L2-resident: B+C = 512 KB) + ONE coalesced dwordx4 store
// (consecutive u -> consecutive 16B -> 1KB/wave stores). Scatter moved to
// the read side where latency is hidable by 8-deep MLP x 4 waves/CU.
__global__ __launch_bounds__(256) void transpose_bc(
        const float* __restrict__ Bm, const float* __restrict__ Cm,
        __half* __restrict__ BC){
    const int u   = blockIdx.x*256 + threadIdx.x;  // 16384 quarter-records
    const int rec = u >> 2, q = u & 3;
    const int b   = rec >> 11;
    const int r   = (rec >> 7) & 15;
    const int c   = rec & 127;
    const int t   = c*16 + r;
    const float* src = (q & 2) ? Cm : Bm;          // q0,1 = B; q2,3 = C
    const int n0  = (q & 1) * 8;
    const long base = ((long)(b*NN + n0))*LL + t;
    __half h[8];
#pragma unroll
    for (int i=0;i<8;++i)
        h[i] = __float2half_rn(src[base + (long)i*LL]);
    ((float4*)BC)[u] = *(const float4*)h;
}

// Block = 2 waves = ONE row-pair (2 consecutive d, same b) — the R0 structure
// (cross-round ledger: CL16/2w is the busy-work floor, ~32 µs chip-wide issue;
// CL8 variants pay +25% KS-scan work; occupancy supply is fixed at 12
// waves/CU by thread count, so sub-128-VGPR diets buy nothing).
// R7 counters == R0 counters byte-for-byte (VGPR 84, conflicts 98K, FETCH/
// WRITE identical); scan is at its structural floor. Unchanged this round.
__global__ __launch_bounds__(128, 3) void ssm_scan(
    const float* __restrict__ x, const float* __restrict__ delta,
    const float* __restrict__ A, const float* __restrict__ Dv,
    const float* __restrict__ z, const __half* __restrict__ BC,
    float* __restrict__ out)
{
    __shared__ float2 sdx[CL*NCH];     // 16 KB
    __shared__ float  wtot[2][2][NN];  // [P/G][row][n] from wave 0 lane 63

    const int lane = threadIdx.x & 63;
    const int w    = threadIdx.x >> 6;
    const int row0 = blockIdx.x*2;           // b*DM + d ; row1 = row0+1
    const int b    = (row0 >= DM) ? 1 : 0;
    const int d0   = row0 - b*DM;
    const int cmy  = w*64 + lane;            // my chunk (0..127)

    const long base0 = (long)row0*LL;
    const long base1 = base0 + LL;
    const float* gd0 = delta + base0; const float* gx0 = x + base0;
    const float* gd1 = delta + base1; const float* gx1 = x + base1;

    // ---- stage packed (d,x) for both rows; wave w covers t in [w*1024, +1024)
    for (int k=0;k<1024;k+=256){
        const int t0 = w*1024 + k + lane*4;
        const float4 dv0 = *(const float4*)(gd0 + t0);
        const float4 xv0 = *(const float4*)(gx0 + t0);
        const float4 dv1 = *(const float4*)(gd1 + t0);
        const float4 xv1 = *(const float4*)(gx1 + t0);
        const float dd0[4]={dv0.x,dv0.y,dv0.z,dv0.w}, xx0[4]={xv0.x,xv0.y,xv0.z,xv0.w};
        const float dd1[4]={dv1.x,dv1.y,dv1.z,dv1.w}, xx1[4]={xv1.x,xv1.y,xv1.z,xv1.w};
#pragma unroll
        for (int j=0;j<4;++j){
            const int t = t0 + j, r = t & 15, c = t >> 4;
            float2 wd; wd.x = packdx(dd0[j], xx0[j]); wd.y = packdx(dd1[j], xx1[j]);
            sdx[r*NCH + (c^r)] = wd;
        }
    }

    // A rows (x LOG2E) and D -> SGPRs (block-uniform)
    float A20[NN], A21[NN];
#pragma unroll
    for (int n=0;n<NN;++n){
        A20[n] = to_sgpr(A[d0*NN+n]     * LOG2E);
        A21[n] = to_sgpr(A[(d0+1)*NN+n] * LOG2E);
    }

    // record for (b, r, chunk cmy): BC + b*65536 + r*4096 + cmy*32 (halfs)
    const __half* bc = BC + (long)b*65536 + cmy*32;

    // ---- phase 1: local chunk scan h0=0 -> G (both rows); dsum -> P
    float G0[NN], G1[NN];
#pragma unroll
    for (int n=0;n<NN;++n){ G0[n]=0.f; G1[n]=0.f; }
    float ds0=0.f, ds1=0.f;
#pragma unroll 2
    for (int r=0;r<CL;++r){
        const float2 wd = sdx[r*NCH + (cmy^r)];
        const float4* rec = (const float4*)(bc + (long)r*4096);
        float bb[16];
        unpack8(rec[0], bb); unpack8(rec[1], bb+8);
        float d_0,x_0,d_1,x_1;
        unpackdx(wd.x, d_0, x_0); unpackdx(wd.y, d_1, x_1);
        ds0 += d_0; ds1 += d_1;
        const float dx0 = d_0*x_0, dx1 = d_1*x_1;
#pragma unroll
        for (int n=0;n<NN;++n){
            const float e0 = fexp2(d_0*A20[n]);
            G0[n] = __builtin_fmaf(e0, G0[n], bb[n]*dx0);
            const float e1 = fexp2(d_1*A21[n]);
            G1[n] = __builtin_fmaf(e1, G1[n], bb[n]*dx1);
        }
    }

    // ---- phase 2: two-level scan
    float h0[NN], h1[NN];
    {
        float P0[NN], P1[NN];
#pragma unroll
        for (int n=0;n<NN;++n){ P0[n]=fexp2(ds0*A20[n]); P1[n]=fexp2(ds1*A21[n]); }
        // inclusive Kogge-Stone within wave
#pragma unroll
        for (int s=1;s<64;s<<=1){
#pragma unroll
            for (int n=0;n<NN;++n){
                const float pl0=__shfl_up(P0[n],s), gl0=__shfl_up(G0[n],s);
                const float pl1=__shfl_up(P1[n],s), gl1=__shfl_up(G1[n],s);
                if (lane >= s){
                    G0[n]=__builtin_fmaf(P0[n],gl0,G0[n]); P0[n]*=pl0;
                    G1[n]=__builtin_fmaf(P1[n],gl1,G1[n]); P1[n]*=pl1;
                }
            }
        }
        // wave-0 totals -> LDS
        if (w==0 && lane==63){
#pragma unroll
            for (int n=0;n<NN;++n){
                wtot[0][0][n]=P0[n]; wtot[1][0][n]=G0[n];
                wtot[0][1][n]=P1[n]; wtot[1][1][n]=G1[n];
            }
        }
        __syncthreads();
        // exclusive within wave, then compose with wave-0 total (wave 1 only)
#pragma unroll
        for (int n=0;n<NN;++n){
            const float pe0=__shfl_up(P0[n],1), ge0=__shfl_up(G0[n],1);
            const float pe1=__shfl_up(P1[n],1), ge1=__shfl_up(G1[n],1);
            const float Px0 = (lane==0)?1.f:pe0, Gx0 = (lane==0)?0.f:ge0;
            const float Px1 = (lane==0)?1.f:pe1, Gx1 = (lane==0)?0.f:ge1;
            const float Gt0 = (w==0)?0.f:wtot[1][0][n];
            const float Gt1 = (w==0)?0.f:wtot[1][1][n];
            h0[n] = __builtin_fmaf(Px0, Gt0, Gx0);
            h1[n] = __builtin_fmaf(Px1, Gt1, Gx1);
        }
    }

    // ---- phase 3: re-scan with true h_start; stash fp32 {y0+x0*D0, y1+x1*D1}
    const float Dd0 = to_sgpr(Dv[d0]), Dd1 = to_sgpr(Dv[d0+1]);
#pragma unroll 2
    for (int r=0;r<CL;++r){
        const int slot = r*NCH + (cmy^r);
        const float2 wd = sdx[slot];
        const float4* rec = (const float4*)(bc + (long)r*4096);
        float bb[16], cc[16];
        unpack8(rec[0], bb); unpack8(rec[1], bb+8);
        unpack8(rec[2], cc); unpack8(rec[3], cc+8);
        float d_0,x_0,d_1,x_1;
        unpackdx(wd.x, d_0, x_0); unpackdx(wd.y, d_1, x_1);
        const float dx0 = d_0*x_0, dx1 = d_1*x_1;
        float ya0=0.f, yb0=0.f, ya1=0.f, yb1=0.f;
#pragma unroll
        for (int n=0;n<NN;n+=2){
            const float e0a = fexp2(d_0*A20[n]);
            h0[n]  =__builtin_fmaf(e0a,h0[n],  bb[n]*dx0);   ya0=__builtin_fmaf(h0[n],  cc[n],  ya0);
            const float e0b = fexp2(d_0*A20[n+1]);
            h0[n+1]=__builtin_fmaf(e0b,h0[n+1],bb[n+1]*dx0); yb0=__builtin_fmaf(h0[n+1],cc[n+1],yb0);
            const float e1a = fexp2(d_1*A21[n]);
            h1[n]  =__builtin_fmaf(e1a,h1[n],  bb[n]*dx1);   ya1=__builtin_fmaf(h1[n],  cc[n],  ya1);
            const float e1b = fexp2(d_1*A21[n+1]);
            h1[n+1]=__builtin_fmaf(e1b,h1[n+1],bb[n+1]*dx1); yb1=__builtin_fmaf(h1[n+1],cc[n+1],yb1);
        }
        float2 yo;
        yo.x = __builtin_fmaf(x_0, Dd0, ya0+yb0);
        yo.y = __builtin_fmaf(x_1, Dd1, ya1+yb1);
        sdx[slot] = yo;                        // silu applied in epilogue
    }

    // ---- epilogue: stream z once per row, coalesced float4 in/out
    const float* gz0 = z + base0; const float* gz1 = z + base1;
    float* go0 = out + base0;     float* go1 = out + base1;
    for (int k=0;k<1024;k+=256){
        const int t0 = w*1024 + k + lane*4;
        const float4 zv0 = *(const float4*)(gz0 + t0);
        const float4 zv1 = *(const float4*)(gz1 + t0);
        const float zz0[4]={zv0.x,zv0.y,zv0.z,zv0.w}, zz1[4]={zv1.x,zv1.y,zv1.z,zv1.w};
        float o0[4], o1[4];
#pragma unroll
        for (int j=0;j<4;++j){
            const int t = t0 + j, r = t & 15, c = t >> 4;
            const float2 wd = sdx[r*NCH + (c^r)];
            const float s0 = frcp(1.f + fexp2(-zz0[j]*LOG2E));
            const float s1 = frcp(1.f + fexp2(-zz1[j]*LOG2E));
            o0[j] = wd.x * (zz0[j]*s0);
            o1[j] = wd.y * (zz1[j]*s1);
        }
        float4 a  = {o0[0],o0[1],o0[2],o0[3]};
        float4 bq = {o1[0],o1[1],o1[2],o1[3]};
        *(float4*)(go0 + t0) = a;
        *(float4*)(go1 + t0) = bq;
    }
}

extern "C" void kernel_launch(void* const* d_in, const int* in_sizes, int n_in,
                              void* d_out, int out_size, void* d_ws, size_t ws_size,
                              hipStream_t stream) {
    const float* x     = (const float*)d_in[0];
    const float* delta = (const float*)d_in[1];
    const float* A     = (const float*)d_in[2];
    const float* B     = (const float*)d_in[3];
    const float* C     = (const float*)d_in[4];
    const float* Dv    = (const float*)d_in[5];
    const float* z     = (const float*)d_in[6];
    float* out = (float*)d_out;

    __half* BC = (__half*)d_ws;               // 131072 halfs = 256 KB

    transpose_bc<<<dim3(64), dim3(256), 0, stream>>>(B, C, BC);
    ssm_scan<<<dim3(DM), dim3(128), 0, stream>>>(x, delta, A, Dv, z, BC, out);
}